// Round 6
// baseline (247.165 us; speedup 1.0000x reference)
//
#include <hip/hip_runtime.h>

typedef unsigned short u16;
typedef __attribute__((ext_vector_type(8))) short short8;   // 8 bf16 (4 VGPRs) MFMA A/B frag
typedef __attribute__((ext_vector_type(4))) short shortx4;  // 4 bf16 (8B)
typedef __attribute__((ext_vector_type(4))) float floatx4;  // MFMA C/D frag

#define S_ 2048
#define D_ 1024
#define DQKV_ 3072
#define H_ 16
#define DH_ 64

#define EXP2F(x) __builtin_amdgcn_exp2f(x)

__device__ __forceinline__ float bf2f(u16 x) {
    union { unsigned int u; float f; } v; v.u = ((unsigned int)x) << 16; return v.f;
}
__device__ __forceinline__ u16 f2bf(float f) {  // RNE
    unsigned int u = __float_as_uint(f);
    return (u16)((u + 0x7fffu + ((u >> 16) & 1u)) >> 16);
}
__device__ __forceinline__ u16 f2bf_fast(float f) {  // round-to-nearest (ties up); operand >= 0
    return (u16)((__float_as_uint(f) + 0x8000u) >> 16);
}

// async global->LDS, 16B per lane; LDS dest is wave-uniform base + lane*16 (m97/m104)
__device__ __forceinline__ void async16(const void* g, void* l) {
    __builtin_amdgcn_global_load_lds(
        (const __attribute__((address_space(1))) unsigned int*)g,
        (__attribute__((address_space(3))) unsigned int*)l, 16, 0, 0);
}

// ---------------- xb = bf16(x), 4096x1024 ----------------
__global__ __launch_bounds__(256) void convert_x(const float* __restrict__ x, u16* __restrict__ xb) {
    const size_t i = ((size_t)blockIdx.x * 256 + threadIdx.x) * 4;
    float4 v = *(const float4*)&x[i];
    shortx4 h;
    h[0] = (short)f2bf(v.x); h[1] = (short)f2bf(v.y);
    h[2] = (short)f2bf(v.z); h[3] = (short)f2bf(v.w);
    *(shortx4*)&xb[i] = h;
}

// ------- fused W transposes: WqkvT[3072][1024] (=[Wq^T;Wk^T;Wv^T]) and WoT[1024][1024] -------
__global__ __launch_bounds__(256) void transpose_w4(const float* __restrict__ Wq, const float* __restrict__ Wk,
                                                    const float* __restrict__ Wv, const float* __restrict__ Wo,
                                                    u16* __restrict__ Wqkvt, u16* __restrict__ Wot) {
    __shared__ u16 tile[32][33];
    const int z = blockIdx.z;
    const float* W = (z == 0) ? Wq : (z == 1) ? Wk : (z == 2) ? Wv : Wo;
    u16* dst = (z == 3) ? Wot : (Wqkvt + (size_t)z * D_ * D_);
    const int tx = threadIdx.x, ty = threadIdx.y;
    const int n0 = blockIdx.x * 32, k0 = blockIdx.y * 32;
#pragma unroll
    for (int r = 0; r < 4; ++r) {
        int k = ty + r * 8;
        tile[k][tx] = f2bf(W[(size_t)(k0 + k) * D_ + n0 + tx]);
    }
    __syncthreads();
#pragma unroll
    for (int r = 0; r < 4; ++r) {
        int n = ty + r * 8;
        dst[(size_t)(n0 + n) * D_ + k0 + tx] = tile[tx][n];
    }
}

// ------- Vt[bh][d][s] = QKV[b*S+s][2048 + h*64 + d]  (per-head V transpose) -------
__global__ __launch_bounds__(256) void transpose_headV(const u16* __restrict__ QKV, u16* __restrict__ Vt) {
    __shared__ u16 tile[64 * 65];
    const int t = threadIdx.x;
    const int bh = blockIdx.y, b = bh >> 4, h = bh & 15;
    const int s0 = blockIdx.x << 6;
#pragma unroll
    for (int i = 0; i < 16; ++i) {
        int idx = t + (i << 8);
        int s = idx >> 6, d = idx & 63;
        tile[s * 65 + d] = QKV[(size_t)(b * S_ + s0 + s) * DQKV_ + 2048 + h * DH_ + d];
    }
    __syncthreads();
#pragma unroll
    for (int i = 0; i < 16; ++i) {
        int idx = t + (i << 8);
        int d = idx >> 6, s = idx & 63;
        Vt[((size_t)bh * DH_ + d) * S_ + s0 + s] = tile[s * 65 + d];
    }
}

// ------- C[M,N] = A[M,K] @ Bt[N,K]^T + bias; bf16 in, fp32 acc -------
// BMxBN tile, BK=32, packed LDS rows (64B) staged via global_load_lds width=16 (m97 pattern).
// 4 waves in 2x2 grid. Bias selected per-1024-col segment.
template <int BM, int BN, bool OUTF32>
__global__ __launch_bounds__(256) void gemm_bt(const u16* __restrict__ A, const u16* __restrict__ Bt,
                                               const float* __restrict__ b0, const float* __restrict__ b1,
                                               const float* __restrict__ b2, void* __restrict__ Cp,
                                               int M, int N, int Kd) {
    constexpr int FI = BM / 32, FJ = BN / 32;
    __shared__ __align__(16) u16 As[BM * 32];  // packed: required by global_load_lds lane-contiguity
    __shared__ __align__(16) u16 Bs[BN * 32];
    const int t = threadIdx.x;
    const int m0 = blockIdx.y * BM, n0 = blockIdx.x * BN;
    const int w = t >> 6, lane = t & 63;
    const int lr = lane & 15, lg = lane >> 4;
    const int wm = (w >> 1) * (BM / 2), wn = (w & 1) * (BN / 2);
    const int srow = lane >> 2, scol = (lane & 3) << 3;  // lane -> (row-in-16, k8)
    floatx4 acc[FI][FJ] = {};

    for (int k0 = 0; k0 < Kd; k0 += 32) {
#pragma unroll
        for (int c = 0; c < BM / 64; ++c) {  // one wave-inst stages 16 rows x 64B = 1KB
            int rbase = (w * (BM / 64) + c) * 16;
            async16(&A[(size_t)(m0 + rbase + srow) * Kd + k0 + scol], &As[rbase * 32]);
        }
#pragma unroll
        for (int c = 0; c < BN / 64; ++c) {
            int rbase = (w * (BN / 64) + c) * 16;
            async16(&Bt[(size_t)(n0 + rbase + srow) * Kd + k0 + scol], &Bs[rbase * 32]);
        }
        __syncthreads();  // drains vmcnt (global_load_lds) before use
        short8 af[FI], bfr[FJ];
#pragma unroll
        for (int i = 0; i < FI; ++i) af[i]  = *(const short8*)&As[(wm + i * 16 + lr) * 32 + lg * 8];
#pragma unroll
        for (int j = 0; j < FJ; ++j) bfr[j] = *(const short8*)&Bs[(wn + j * 16 + lr) * 32 + lg * 8];
#pragma unroll
        for (int i = 0; i < FI; ++i)
#pragma unroll
            for (int j = 0; j < FJ; ++j)
                acc[i][j] = __builtin_amdgcn_mfma_f32_16x16x32_bf16(af[i], bfr[j], acc[i][j], 0, 0, 0);
        __syncthreads();
    }

#pragma unroll
    for (int j = 0; j < FJ; ++j) {
        int col = n0 + wn + j * 16 + lr;
        const float* bp = (col < 1024) ? b0 : (col < 2048) ? b1 : b2;
        float bv = bp[col & 1023];
#pragma unroll
        for (int i = 0; i < FI; ++i) {
            int rb = m0 + wm + i * 16 + lg * 4;
#pragma unroll
            for (int ii = 0; ii < 4; ++ii) {
                float val = acc[i][j][ii] + bv;
                if (OUTF32) ((float*)Cp)[(size_t)(rb + ii) * N + col] = val;
                else        ((u16*)Cp)[(size_t)(rb + ii) * N + col] = f2bf(val);
            }
        }
    }
}

// ---------------- MFMA flash attention, single 64-q tile per block ----------------
// grid (bh=32, qidx=32); qt = 31-qidx (LPT). 4 waves x 16 q-rows.
// No-max softmax (scores bounded -> exp2 directly; exact by shift-invariance).
// Next K/V tile prefetched to registers right after the barrier (hides global latency).
__global__ __launch_bounds__(256) void attn_mfma(const u16* __restrict__ QKV, const u16* __restrict__ Vt,
                                                 u16* __restrict__ O) {
    __shared__ __align__(16) u16 Ks[64 * 72];      // [key][d] (B^T layout), 144B rows, conflict-free frags
    __shared__ __align__(16) u16 Vs[64 * 72];      // [d][key]
    __shared__ __align__(16) u16 Ps[4 * 16 * 76];  // per-wave P [q][key]
    const int t = threadIdx.x, w = t >> 6, lane = t & 63;
    const int lr = lane & 15, lg = lane >> 4;
    const int bh = blockIdx.x, b = bh >> 4, h = bh & 15;
    const int qt = 31 - blockIdx.y;
    const int q0 = qt << 6;
    const float cs = 0.18033688f;  // (1/sqrt(64)) * log2(e)

    const u16* Kb  = QKV + (size_t)b * S_ * DQKV_ + 1024 + h * DH_;  // row stride DQKV_
    const u16* Vtb = Vt + (size_t)bh * DH_ * S_;                     // row stride S_
    u16* Pw = Ps + w * (16 * 76);

    const int srow = t >> 3, sc8 = (t & 7) << 3;  // staging map (with +256 for second chunk)

    short8 qf[2];  // Q A-frags: A[m=lr][k=ks*32+lg*8+j]
#pragma unroll
    for (int ks = 0; ks < 2; ++ks)
        qf[ks] = *(const short8*)&QKV[(size_t)(b * S_ + q0 + w * 16 + lr) * DQKV_ + h * DH_ + ks * 32 + lg * 8];

    floatx4 of[4] = {};  // O [16q][64d] C-layout: row=lg*4+ii, col=j*16+lr
    float lsum[4] = {0.f, 0.f, 0.f, 0.f};

    uint4 kreg[2], vreg[2];
#pragma unroll
    for (int c = 0; c < 2; ++c) {  // prefetch tile 0
        int row = srow + (c << 5);
        kreg[c] = *(const uint4*)&Kb[(size_t)row * DQKV_ + sc8];
        vreg[c] = *(const uint4*)&Vtb[(size_t)row * S_ + sc8];
    }

    for (int kb = 0; kb <= qt; ++kb) {
#pragma unroll
        for (int c = 0; c < 2; ++c) {  // write staged tile to LDS
            int row = srow + (c << 5);
            *(uint4*)&Ks[row * 72 + sc8] = kreg[c];
            *(uint4*)&Vs[row * 72 + sc8] = vreg[c];
        }
        __syncthreads();
        if (kb < qt) {  // prefetch next tile; latency overlaps compute below
            const int K1 = (kb + 1) << 6;
#pragma unroll
            for (int c = 0; c < 2; ++c) {
                int row = srow + (c << 5);
                kreg[c] = *(const uint4*)&Kb[(size_t)(K1 + row) * DQKV_ + sc8];
                vreg[c] = *(const uint4*)&Vtb[(size_t)row * S_ + K1 + sc8];
            }
        }

        floatx4 sf[4] = {};  // S [16q][64keys]
#pragma unroll
        for (int ks = 0; ks < 2; ++ks)
#pragma unroll
            for (int j = 0; j < 4; ++j) {
                short8 kf = *(const short8*)&Ks[(j * 16 + lr) * 72 + ks * 32 + lg * 8];
                sf[j] = __builtin_amdgcn_mfma_f32_16x16x32_bf16(qf[ks], kf, sf[j], 0, 0, 0);
            }

        // no-max softmax: e = 2^(s*cs); masked -> 0; l accumulated per-lane
        const bool diag = (kb == qt);
#pragma unroll
        for (int j = 0; j < 4; ++j)
#pragma unroll
            for (int ii = 0; ii < 4; ++ii) {
                float ev = EXP2F(sf[j][ii] * cs);
                if (diag && (j * 16 + lr > w * 16 + lg * 4 + ii)) ev = 0.f;
                lsum[ii] += ev;
                Pw[(lg * 4 + ii) * 76 + j * 16 + lr] = f2bf_fast(ev);  // C->LDS
            }

#pragma unroll
        for (int ks = 0; ks < 2; ++ks) {
            union { short8 v; shortx4 hh[2]; } pa;  // P A-frag: two 8B reads
            pa.hh[0] = *(const shortx4*)&Pw[lr * 76 + ks * 32 + lg * 8];
            pa.hh[1] = *(const shortx4*)&Pw[lr * 76 + ks * 32 + lg * 8 + 4];
#pragma unroll
            for (int j = 0; j < 4; ++j) {
                short8 vf = *(const short8*)&Vs[(j * 16 + lr) * 72 + ks * 32 + lg * 8];
                of[j] = __builtin_amdgcn_mfma_f32_16x16x32_bf16(pa.v, vf, of[j], 0, 0, 0);
            }
        }
        __syncthreads();
    }

    float rinv[4];
#pragma unroll
    for (int ii = 0; ii < 4; ++ii) {  // one l-reduction for the whole kernel
        float s = lsum[ii];
#pragma unroll
        for (int off = 1; off < 16; off <<= 1) s += __shfl_xor(s, off);
        rinv[ii] = 1.f / s;
    }
#pragma unroll
    for (int j = 0; j < 4; ++j)
#pragma unroll
        for (int ii = 0; ii < 4; ++ii)
            O[(size_t)(b * S_ + q0 + w * 16 + lg * 4 + ii) * D_ + h * DH_ + j * 16 + lr] =
                f2bf(of[j][ii] * rinv[ii]);
}

extern "C" void kernel_launch(void* const* d_in, const int* in_sizes, int n_in,
                              void* d_out, int out_size, void* d_ws, size_t ws_size,
                              hipStream_t stream) {
    (void)in_sizes; (void)n_in; (void)out_size; (void)ws_size;
    const float* x  = (const float*)d_in[0];
    const float* Wq = (const float*)d_in[1];
    const float* bq = (const float*)d_in[2];
    const float* Wk = (const float*)d_in[3];
    const float* bk = (const float*)d_in[4];
    const float* Wv = (const float*)d_in[5];
    const float* bv = (const float*)d_in[6];
    const float* Wo = (const float*)d_in[7];
    const float* bo = (const float*)d_in[8];

    // ws layout (u16 elems), 48 MB total:
    //   [0,3M) WqkvT  [3M,4M) WoT  [4M,16M) QKV  [16M,20M) Vt  [20M,24M) xbf -> reused as Am
    u16* ws    = (u16*)d_ws;
    u16* WqkvT = ws;
    u16* WoT   = ws + (size_t)3 * (1 << 20);
    u16* QKV   = ws + (size_t)4 * (1 << 20);
    u16* Vtm   = ws + (size_t)16 * (1 << 20);
    u16* xbf   = ws + (size_t)20 * (1 << 20);
    u16* Am    = ws + (size_t)20 * (1 << 20);

    convert_x<<<4096, 256, 0, stream>>>(x, xbf);
    transpose_w4<<<dim3(32, 32, 4), dim3(32, 8), 0, stream>>>(Wq, Wk, Wv, Wo, WqkvT, WoT);

    // QKV = xbf @ WqkvT^T + [bq|bk|bv]  (M=4096, N=3072)
    gemm_bt<128, 128, false><<<dim3(DQKV_ / 128, 4096 / 128), 256, 0, stream>>>(
        xbf, WqkvT, bq, bk, bv, QKV, 4096, DQKV_, 1024);

    transpose_headV<<<dim3(32, 32), 256, 0, stream>>>(QKV, Vtm);

    attn_mfma<<<dim3(32, 32), 256, 0, stream>>>(QKV, Vtm, Am);

    // out = Am @ WoT^T + bo  (M=4096, N=1024), fp32 out
    gemm_bt<64, 128, true><<<dim3(1024 / 128, 4096 / 64), 256, 0, stream>>>(
        Am, WoT, bo, bo, bo, d_out, 4096, 1024, 1024);
}

// Round 7
// 245.716 us; speedup vs baseline: 1.0059x; 1.0059x over previous
//
#include <hip/hip_runtime.h>

typedef unsigned short u16;
typedef __attribute__((ext_vector_type(8))) short short8;   // 8 bf16 (4 VGPRs) MFMA A/B frag
typedef __attribute__((ext_vector_type(4))) short shortx4;  // 4 bf16 (8B)
typedef __attribute__((ext_vector_type(4))) float floatx4;  // MFMA C/D frag

#define S_ 2048
#define D_ 1024
#define DQKV_ 3072
#define H_ 16
#define DH_ 64

#define EXP2F(x) __builtin_amdgcn_exp2f(x)

__device__ __forceinline__ float bf2f(u16 x) {
    union { unsigned int u; float f; } v; v.u = ((unsigned int)x) << 16; return v.f;
}
__device__ __forceinline__ u16 f2bf(float f) {  // RNE
    unsigned int u = __float_as_uint(f);
    return (u16)((u + 0x7fffu + ((u >> 16) & 1u)) >> 16);
}
__device__ __forceinline__ u16 f2bf_fast(float f) {  // round-to-nearest (ties up); operand >= 0
    return (u16)((__float_as_uint(f) + 0x8000u) >> 16);
}

// async global->LDS, 16B per lane; LDS dest is wave-uniform base + lane*16 (m97/m104)
__device__ __forceinline__ void async16(const void* g, void* l) {
    __builtin_amdgcn_global_load_lds(
        (const __attribute__((address_space(1))) unsigned int*)g,
        (__attribute__((address_space(3))) unsigned int*)l, 16, 0, 0);
}

// ---------------- xb = bf16(x), 4096x1024 ----------------
__global__ __launch_bounds__(256) void convert_x(const float* __restrict__ x, u16* __restrict__ xb) {
    const size_t i = ((size_t)blockIdx.x * 256 + threadIdx.x) * 4;
    float4 v = *(const float4*)&x[i];
    shortx4 h;
    h[0] = (short)f2bf(v.x); h[1] = (short)f2bf(v.y);
    h[2] = (short)f2bf(v.z); h[3] = (short)f2bf(v.w);
    *(shortx4*)&xb[i] = h;
}

// ------- fused W transposes: WqkvT[3072][1024] (=[Wq^T;Wk^T;Wv^T]) and WoT[1024][1024] -------
__global__ __launch_bounds__(256) void transpose_w4(const float* __restrict__ Wq, const float* __restrict__ Wk,
                                                    const float* __restrict__ Wv, const float* __restrict__ Wo,
                                                    u16* __restrict__ Wqkvt, u16* __restrict__ Wot) {
    __shared__ u16 tile[32][33];
    const int z = blockIdx.z;
    const float* W = (z == 0) ? Wq : (z == 1) ? Wk : (z == 2) ? Wv : Wo;
    u16* dst = (z == 3) ? Wot : (Wqkvt + (size_t)z * D_ * D_);
    const int tx = threadIdx.x, ty = threadIdx.y;
    const int n0 = blockIdx.x * 32, k0 = blockIdx.y * 32;
#pragma unroll
    for (int r = 0; r < 4; ++r) {
        int k = ty + r * 8;
        tile[k][tx] = f2bf(W[(size_t)(k0 + k) * D_ + n0 + tx]);
    }
    __syncthreads();
#pragma unroll
    for (int r = 0; r < 4; ++r) {
        int n = ty + r * 8;
        dst[(size_t)(n0 + n) * D_ + k0 + tx] = tile[tx][n];
    }
}

// ------- Vt[bh][d][s] = QKV[b*S+s][2048 + h*64 + d]  (per-head V transpose) -------
__global__ __launch_bounds__(256) void transpose_headV(const u16* __restrict__ QKV, u16* __restrict__ Vt) {
    __shared__ u16 tile[64 * 65];
    const int t = threadIdx.x;
    const int bh = blockIdx.y, b = bh >> 4, h = bh & 15;
    const int s0 = blockIdx.x << 6;
#pragma unroll
    for (int i = 0; i < 16; ++i) {
        int idx = t + (i << 8);
        int s = idx >> 6, d = idx & 63;
        tile[s * 65 + d] = QKV[(size_t)(b * S_ + s0 + s) * DQKV_ + 2048 + h * DH_ + d];
    }
    __syncthreads();
#pragma unroll
    for (int i = 0; i < 16; ++i) {
        int idx = t + (i << 8);
        int d = idx >> 6, s = idx & 63;
        Vt[((size_t)bh * DH_ + d) * S_ + s0 + s] = tile[s * 65 + d];
    }
}

// ------- C[M,N] = A[M,K] @ Bt[N,K]^T + bias; bf16 in, fp32 acc -------
// BMxBN tile, BK=32, packed LDS rows (64B) staged via global_load_lds width=16 (m97 pattern).
// 4 waves in 2x2 grid. Bias selected per-1024-col segment.
template <int BM, int BN, bool OUTF32>
__global__ __launch_bounds__(256) void gemm_bt(const u16* __restrict__ A, const u16* __restrict__ Bt,
                                               const float* __restrict__ b0, const float* __restrict__ b1,
                                               const float* __restrict__ b2, void* __restrict__ Cp,
                                               int M, int N, int Kd) {
    constexpr int FI = BM / 32, FJ = BN / 32;
    __shared__ __align__(16) u16 As[BM * 32];  // packed: required by global_load_lds lane-contiguity
    __shared__ __align__(16) u16 Bs[BN * 32];
    const int t = threadIdx.x;
    const int m0 = blockIdx.y * BM, n0 = blockIdx.x * BN;
    const int w = t >> 6, lane = t & 63;
    const int lr = lane & 15, lg = lane >> 4;
    const int wm = (w >> 1) * (BM / 2), wn = (w & 1) * (BN / 2);
    const int srow = lane >> 2, scol = (lane & 3) << 3;  // lane -> (row-in-16, k8)
    floatx4 acc[FI][FJ] = {};

    for (int k0 = 0; k0 < Kd; k0 += 32) {
#pragma unroll
        for (int c = 0; c < BM / 64; ++c) {  // one wave-inst stages 16 rows x 64B = 1KB
            int rbase = (w * (BM / 64) + c) * 16;
            async16(&A[(size_t)(m0 + rbase + srow) * Kd + k0 + scol], &As[rbase * 32]);
        }
#pragma unroll
        for (int c = 0; c < BN / 64; ++c) {
            int rbase = (w * (BN / 64) + c) * 16;
            async16(&Bt[(size_t)(n0 + rbase + srow) * Kd + k0 + scol], &Bs[rbase * 32]);
        }
        __syncthreads();  // drains vmcnt (global_load_lds) before use
        short8 af[FI], bfr[FJ];
#pragma unroll
        for (int i = 0; i < FI; ++i) af[i]  = *(const short8*)&As[(wm + i * 16 + lr) * 32 + lg * 8];
#pragma unroll
        for (int j = 0; j < FJ; ++j) bfr[j] = *(const short8*)&Bs[(wn + j * 16 + lr) * 32 + lg * 8];
#pragma unroll
        for (int i = 0; i < FI; ++i)
#pragma unroll
            for (int j = 0; j < FJ; ++j)
                acc[i][j] = __builtin_amdgcn_mfma_f32_16x16x32_bf16(af[i], bfr[j], acc[i][j], 0, 0, 0);
        __syncthreads();
    }

#pragma unroll
    for (int j = 0; j < FJ; ++j) {
        int col = n0 + wn + j * 16 + lr;
        const float* bp = (col < 1024) ? b0 : (col < 2048) ? b1 : b2;
        float bv = bp[col & 1023];
#pragma unroll
        for (int i = 0; i < FI; ++i) {
            int rb = m0 + wm + i * 16 + lg * 4;
#pragma unroll
            for (int ii = 0; ii < 4; ++ii) {
                float val = acc[i][j][ii] + bv;
                if (OUTF32) ((float*)Cp)[(size_t)(rb + ii) * N + col] = val;
                else        ((u16*)Cp)[(size_t)(rb + ii) * N + col] = f2bf(val);
            }
        }
    }
}

// ---------------- MFMA flash attention, single 64-q tile per block ----------------
// grid (bh=32, qidx=32); qt = 31-qidx (LPT). 4 waves x 16 q-rows.
// No-max softmax (scores bounded -> exp2 directly; exact by shift-invariance).
// Next K/V tile prefetched to registers after the barrier.
// __launch_bounds__(256,4): VGPR budget 128 so the prefetch regs do NOT spill
// (round 6: allocator picked 60 VGPR and spilled -> 87 MB scratch writes/dispatch).
__global__ __launch_bounds__(256, 4) void attn_mfma(const u16* __restrict__ QKV, const u16* __restrict__ Vt,
                                                    u16* __restrict__ O) {
    __shared__ __align__(16) u16 Ks[64 * 72];      // [key][d] (B^T layout), 144B rows
    __shared__ __align__(16) u16 Vs[64 * 72];      // [d][key]
    __shared__ __align__(16) u16 Ps[4 * 16 * 76];  // per-wave P [q][key]
    const int t = threadIdx.x, w = t >> 6, lane = t & 63;
    const int lr = lane & 15, lg = lane >> 4;
    const int bh = blockIdx.x, b = bh >> 4, h = bh & 15;
    const int qt = 31 - blockIdx.y;
    const int q0 = qt << 6;
    const float cs = 0.18033688f;  // (1/sqrt(64)) * log2(e)

    const u16* Kb  = QKV + (size_t)b * S_ * DQKV_ + 1024 + h * DH_;  // row stride DQKV_
    const u16* Vtb = Vt + (size_t)bh * DH_ * S_;                     // row stride S_
    u16* Pw = Ps + w * (16 * 76);

    const int srow = t >> 3, sc8 = (t & 7) << 3;  // staging map

    short8 qf[2];  // Q A-frags: A[m=lr][k=ks*32+lg*8+j]
#pragma unroll
    for (int ks = 0; ks < 2; ++ks)
        qf[ks] = *(const short8*)&QKV[(size_t)(b * S_ + q0 + w * 16 + lr) * DQKV_ + h * DH_ + ks * 32 + lg * 8];

    floatx4 of[4] = {};  // O [16q][64d] C-layout: row=lg*4+ii, col=j*16+lr
    float lsum[4] = {0.f, 0.f, 0.f, 0.f};

    uint4 kreg[2], vreg[2];
#pragma unroll
    for (int c = 0; c < 2; ++c) {  // prefetch tile 0
        int row = srow + (c << 5);
        kreg[c] = *(const uint4*)&Kb[(size_t)row * DQKV_ + sc8];
        vreg[c] = *(const uint4*)&Vtb[(size_t)row * S_ + sc8];
    }

    for (int kb = 0; kb <= qt; ++kb) {
#pragma unroll
        for (int c = 0; c < 2; ++c) {  // write staged tile to LDS
            int row = srow + (c << 5);
            *(uint4*)&Ks[row * 72 + sc8] = kreg[c];
            *(uint4*)&Vs[row * 72 + sc8] = vreg[c];
        }
        __syncthreads();
        if (kb < qt) {  // prefetch next tile; latency overlaps compute below
            const int K1 = (kb + 1) << 6;
#pragma unroll
            for (int c = 0; c < 2; ++c) {
                int row = srow + (c << 5);
                kreg[c] = *(const uint4*)&Kb[(size_t)(K1 + row) * DQKV_ + sc8];
                vreg[c] = *(const uint4*)&Vtb[(size_t)row * S_ + K1 + sc8];
            }
        }

        floatx4 sf[4] = {};  // S [16q][64keys]
#pragma unroll
        for (int ks = 0; ks < 2; ++ks)
#pragma unroll
            for (int j = 0; j < 4; ++j) {
                short8 kf = *(const short8*)&Ks[(j * 16 + lr) * 72 + ks * 32 + lg * 8];
                sf[j] = __builtin_amdgcn_mfma_f32_16x16x32_bf16(qf[ks], kf, sf[j], 0, 0, 0);
            }

        // no-max softmax: e = 2^(s*cs); masked -> 0; l accumulated per-lane
        const bool diag = (kb == qt);
#pragma unroll
        for (int j = 0; j < 4; ++j)
#pragma unroll
            for (int ii = 0; ii < 4; ++ii) {
                float ev = EXP2F(sf[j][ii] * cs);
                if (diag && (j * 16 + lr > w * 16 + lg * 4 + ii)) ev = 0.f;
                lsum[ii] += ev;
                Pw[(lg * 4 + ii) * 76 + j * 16 + lr] = f2bf_fast(ev);  // C->LDS
            }

#pragma unroll
        for (int ks = 0; ks < 2; ++ks) {
            union { short8 v; shortx4 hh[2]; } pa;  // P A-frag: two 8B reads
            pa.hh[0] = *(const shortx4*)&Pw[lr * 76 + ks * 32 + lg * 8];
            pa.hh[1] = *(const shortx4*)&Pw[lr * 76 + ks * 32 + lg * 8 + 4];
#pragma unroll
            for (int j = 0; j < 4; ++j) {
                short8 vf = *(const short8*)&Vs[(j * 16 + lr) * 72 + ks * 32 + lg * 8];
                of[j] = __builtin_amdgcn_mfma_f32_16x16x32_bf16(pa.v, vf, of[j], 0, 0, 0);
            }
        }
        __syncthreads();
    }

    float rinv[4];
#pragma unroll
    for (int ii = 0; ii < 4; ++ii) {  // one l-reduction for the whole kernel
        float s = lsum[ii];
#pragma unroll
        for (int off = 1; off < 16; off <<= 1) s += __shfl_xor(s, off);
        rinv[ii] = 1.f / s;
    }
#pragma unroll
    for (int j = 0; j < 4; ++j)
#pragma unroll
        for (int ii = 0; ii < 4; ++ii)
            O[(size_t)(b * S_ + q0 + w * 16 + lg * 4 + ii) * D_ + h * DH_ + j * 16 + lr] =
                f2bf(of[j][ii] * rinv[ii]);
}

extern "C" void kernel_launch(void* const* d_in, const int* in_sizes, int n_in,
                              void* d_out, int out_size, void* d_ws, size_t ws_size,
                              hipStream_t stream) {
    (void)in_sizes; (void)n_in; (void)out_size; (void)ws_size;
    const float* x  = (const float*)d_in[0];
    const float* Wq = (const float*)d_in[1];
    const float* bq = (const float*)d_in[2];
    const float* Wk = (const float*)d_in[3];
    const float* bk = (const float*)d_in[4];
    const float* Wv = (const float*)d_in[5];
    const float* bv = (const float*)d_in[6];
    const float* Wo = (const float*)d_in[7];
    const float* bo = (const float*)d_in[8];

    // ws layout (u16 elems), 48 MB total:
    //   [0,3M) WqkvT  [3M,4M) WoT  [4M,16M) QKV  [16M,20M) Vt  [20M,24M) xbf -> reused as Am
    u16* ws    = (u16*)d_ws;
    u16* WqkvT = ws;
    u16* WoT   = ws + (size_t)3 * (1 << 20);
    u16* QKV   = ws + (size_t)4 * (1 << 20);
    u16* Vtm   = ws + (size_t)16 * (1 << 20);
    u16* xbf   = ws + (size_t)20 * (1 << 20);
    u16* Am    = ws + (size_t)20 * (1 << 20);

    convert_x<<<4096, 256, 0, stream>>>(x, xbf);
    transpose_w4<<<dim3(32, 32, 4), dim3(32, 8), 0, stream>>>(Wq, Wk, Wv, Wo, WqkvT, WoT);

    // QKV = xbf @ WqkvT^T + [bq|bk|bv]  (M=4096, N=3072)
    gemm_bt<128, 128, false><<<dim3(DQKV_ / 128, 4096 / 128), 256, 0, stream>>>(
        xbf, WqkvT, bq, bk, bv, QKV, 4096, DQKV_, 1024);

    transpose_headV<<<dim3(32, 32), 256, 0, stream>>>(QKV, Vtm);

    attn_mfma<<<dim3(32, 32), 256, 0, stream>>>(QKV, Vtm, Am);

    // out = Am @ WoT^T + bo  (M=4096, N=1024), fp32 out
    gemm_bt<64, 128, true><<<dim3(1024 / 128, 4096 / 64), 256, 0, stream>>>(
        Am, WoT, bo, bo, bo, d_out, 4096, 1024, 1024);
}

// Round 8
// 212.080 us; speedup vs baseline: 1.1654x; 1.1586x over previous
//
#include <hip/hip_runtime.h>

typedef unsigned short u16;
typedef __attribute__((ext_vector_type(8))) short short8;   // 8 bf16 (4 VGPRs) MFMA A/B frag
typedef __attribute__((ext_vector_type(4))) short shortx4;  // 4 bf16 (8B)
typedef __attribute__((ext_vector_type(4))) float floatx4;  // MFMA C/D frag

#define S_ 2048
#define D_ 1024
#define DQKV_ 3072
#define H_ 16
#define DH_ 64

#define EXP2F(x) __builtin_amdgcn_exp2f(x)

__device__ __forceinline__ float bf2f(u16 x) {
    union { unsigned int u; float f; } v; v.u = ((unsigned int)x) << 16; return v.f;
}
__device__ __forceinline__ u16 f2bf(float f) {  // RNE
    unsigned int u = __float_as_uint(f);
    return (u16)((u + 0x7fffu + ((u >> 16) & 1u)) >> 16);
}
__device__ __forceinline__ u16 f2bf_fast(float f) {  // round-to-nearest (ties up); operand >= 0
    return (u16)((__float_as_uint(f) + 0x8000u) >> 16);
}

// async global->LDS, 16B per lane; LDS dest is wave-uniform base + lane*16 (m97/m104)
__device__ __forceinline__ void async16(const void* g, void* l) {
    __builtin_amdgcn_global_load_lds(
        (const __attribute__((address_space(1))) unsigned int*)g,
        (__attribute__((address_space(3))) unsigned int*)l, 16, 0, 0);
}

// ---------------- xb = bf16(x), 4096x1024 ----------------
__global__ __launch_bounds__(256) void convert_x(const float* __restrict__ x, u16* __restrict__ xb) {
    const size_t i = ((size_t)blockIdx.x * 256 + threadIdx.x) * 4;
    float4 v = *(const float4*)&x[i];
    shortx4 h;
    h[0] = (short)f2bf(v.x); h[1] = (short)f2bf(v.y);
    h[2] = (short)f2bf(v.z); h[3] = (short)f2bf(v.w);
    *(shortx4*)&xb[i] = h;
}

// ------- fused W transposes: WqkvT[3072][1024] (=[Wq^T;Wk^T;Wv^T]) and WoT[1024][1024] -------
__global__ __launch_bounds__(256) void transpose_w4(const float* __restrict__ Wq, const float* __restrict__ Wk,
                                                    const float* __restrict__ Wv, const float* __restrict__ Wo,
                                                    u16* __restrict__ Wqkvt, u16* __restrict__ Wot) {
    __shared__ u16 tile[32][33];
    const int z = blockIdx.z;
    const float* W = (z == 0) ? Wq : (z == 1) ? Wk : (z == 2) ? Wv : Wo;
    u16* dst = (z == 3) ? Wot : (Wqkvt + (size_t)z * D_ * D_);
    const int tx = threadIdx.x, ty = threadIdx.y;
    const int n0 = blockIdx.x * 32, k0 = blockIdx.y * 32;
#pragma unroll
    for (int r = 0; r < 4; ++r) {
        int k = ty + r * 8;
        tile[k][tx] = f2bf(W[(size_t)(k0 + k) * D_ + n0 + tx]);
    }
    __syncthreads();
#pragma unroll
    for (int r = 0; r < 4; ++r) {
        int n = ty + r * 8;
        dst[(size_t)(n0 + n) * D_ + k0 + tx] = tile[tx][n];
    }
}

// ------- Vt[bh][d][s] = QKV[b*S+s][2048 + h*64 + d]  (per-head V transpose) -------
__global__ __launch_bounds__(256) void transpose_headV(const u16* __restrict__ QKV, u16* __restrict__ Vt) {
    __shared__ u16 tile[64 * 65];
    const int t = threadIdx.x;
    const int bh = blockIdx.y, b = bh >> 4, h = bh & 15;
    const int s0 = blockIdx.x << 6;
#pragma unroll
    for (int i = 0; i < 16; ++i) {
        int idx = t + (i << 8);
        int s = idx >> 6, d = idx & 63;
        tile[s * 65 + d] = QKV[(size_t)(b * S_ + s0 + s) * DQKV_ + 2048 + h * DH_ + d];
    }
    __syncthreads();
#pragma unroll
    for (int i = 0; i < 16; ++i) {
        int idx = t + (i << 8);
        int d = idx >> 6, s = idx & 63;
        Vt[((size_t)bh * DH_ + d) * S_ + s0 + s] = tile[s * 65 + d];
    }
}

// ------- C[M,N] = A[M,K] @ Bt[N,K]^T + bias; bf16 in, fp32 acc -------
// BMxBN tile, BK=32, packed LDS rows (64B) staged via global_load_lds width=16 (m97 pattern).
// 4 waves in 2x2 grid. Bias selected per-1024-col segment.
template <int BM, int BN, bool OUTF32>
__global__ __launch_bounds__(256) void gemm_bt(const u16* __restrict__ A, const u16* __restrict__ Bt,
                                               const float* __restrict__ b0, const float* __restrict__ b1,
                                               const float* __restrict__ b2, void* __restrict__ Cp,
                                               int M, int N, int Kd) {
    constexpr int FI = BM / 32, FJ = BN / 32;
    __shared__ __align__(16) u16 As[BM * 32];  // packed: required by global_load_lds lane-contiguity
    __shared__ __align__(16) u16 Bs[BN * 32];
    const int t = threadIdx.x;
    const int m0 = blockIdx.y * BM, n0 = blockIdx.x * BN;
    const int w = t >> 6, lane = t & 63;
    const int lr = lane & 15, lg = lane >> 4;
    const int wm = (w >> 1) * (BM / 2), wn = (w & 1) * (BN / 2);
    const int srow = lane >> 2, scol = (lane & 3) << 3;  // lane -> (row-in-16, k8)
    floatx4 acc[FI][FJ] = {};

    for (int k0 = 0; k0 < Kd; k0 += 32) {
#pragma unroll
        for (int c = 0; c < BM / 64; ++c) {  // one wave-inst stages 16 rows x 64B = 1KB
            int rbase = (w * (BM / 64) + c) * 16;
            async16(&A[(size_t)(m0 + rbase + srow) * Kd + k0 + scol], &As[rbase * 32]);
        }
#pragma unroll
        for (int c = 0; c < BN / 64; ++c) {
            int rbase = (w * (BN / 64) + c) * 16;
            async16(&Bt[(size_t)(n0 + rbase + srow) * Kd + k0 + scol], &Bs[rbase * 32]);
        }
        __syncthreads();  // drains vmcnt (global_load_lds) before use
        short8 af[FI], bfr[FJ];
#pragma unroll
        for (int i = 0; i < FI; ++i) af[i]  = *(const short8*)&As[(wm + i * 16 + lr) * 32 + lg * 8];
#pragma unroll
        for (int j = 0; j < FJ; ++j) bfr[j] = *(const short8*)&Bs[(wn + j * 16 + lr) * 32 + lg * 8];
#pragma unroll
        for (int i = 0; i < FI; ++i)
#pragma unroll
            for (int j = 0; j < FJ; ++j)
                acc[i][j] = __builtin_amdgcn_mfma_f32_16x16x32_bf16(af[i], bfr[j], acc[i][j], 0, 0, 0);
        __syncthreads();
    }

#pragma unroll
    for (int j = 0; j < FJ; ++j) {
        int col = n0 + wn + j * 16 + lr;
        const float* bp = (col < 1024) ? b0 : (col < 2048) ? b1 : b2;
        float bv = bp[col & 1023];
#pragma unroll
        for (int i = 0; i < FI; ++i) {
            int rb = m0 + wm + i * 16 + lg * 4;
#pragma unroll
            for (int ii = 0; ii < 4; ++ii) {
                float val = acc[i][j][ii] + bv;
                if (OUTF32) ((float*)Cp)[(size_t)(rb + ii) * N + col] = val;
                else        ((u16*)Cp)[(size_t)(rb + ii) * N + col] = f2bf(val);
            }
        }
    }
}

// ---------------- MFMA flash attention, single 64-q tile per block ----------------
// grid (bh=32, qidx=32); qt = 31-qidx (LPT). 4 waves x 16 q-rows.
// No-max softmax (scores bounded -> exp2 directly; exact by shift-invariance).
// Staging is load->immediate-LDS-write (R5 pattern): transient regs, NO long live
// ranges. (R6/R7's held prefetch regs forced ~90MB/dispatch scratch spill: the
// unified VGPR+AGPR file can't fund 16 extra VGPRs across the MFMA region.)
__global__ __launch_bounds__(256) void attn_mfma(const u16* __restrict__ QKV, const u16* __restrict__ Vt,
                                                 u16* __restrict__ O) {
    __shared__ __align__(16) u16 Ks[64 * 72];      // [key][d] (B^T layout), 144B rows
    __shared__ __align__(16) u16 Vs[64 * 72];      // [d][key]
    __shared__ __align__(16) u16 Ps[4 * 16 * 76];  // per-wave P [q][key]
    const int t = threadIdx.x, w = t >> 6, lane = t & 63;
    const int lr = lane & 15, lg = lane >> 4;
    const int bh = blockIdx.x, b = bh >> 4, h = bh & 15;
    const int qt = 31 - blockIdx.y;
    const int q0 = qt << 6;
    const float cs = 0.18033688f;  // (1/sqrt(64)) * log2(e)

    const u16* Kb  = QKV + (size_t)b * S_ * DQKV_ + 1024 + h * DH_;  // row stride DQKV_
    const u16* Vtb = Vt + (size_t)bh * DH_ * S_;                     // row stride S_
    u16* Pw = Ps + w * (16 * 76);

    short8 qf[2];  // Q A-frags: A[m=lr][k=ks*32+lg*8+j]
#pragma unroll
    for (int ks = 0; ks < 2; ++ks)
        qf[ks] = *(const short8*)&QKV[(size_t)(b * S_ + q0 + w * 16 + lr) * DQKV_ + h * DH_ + ks * 32 + lg * 8];

    floatx4 of[4] = {};  // O [16q][64d] C-layout: row=lg*4+ii, col=j*16+lr
    float lsum[4] = {0.f, 0.f, 0.f, 0.f};

    for (int kb = 0; kb <= qt; ++kb) {
        const int K0 = kb << 6;
#pragma unroll
        for (int c = 0; c < 2; ++c) {  // stage K-tile + V^T-tile (transient regs)
            int idx = t + (c << 8);
            int row = idx >> 3, c8 = (idx & 7) << 3;
            *(uint4*)&Ks[row * 72 + c8] = *(const uint4*)&Kb[(size_t)(K0 + row) * DQKV_ + c8];
            *(uint4*)&Vs[row * 72 + c8] = *(const uint4*)&Vtb[(size_t)row * S_ + K0 + c8];
        }
        __syncthreads();

        floatx4 sf[4] = {};  // S [16q][64keys]
#pragma unroll
        for (int ks = 0; ks < 2; ++ks)
#pragma unroll
            for (int j = 0; j < 4; ++j) {
                short8 kf = *(const short8*)&Ks[(j * 16 + lr) * 72 + ks * 32 + lg * 8];
                sf[j] = __builtin_amdgcn_mfma_f32_16x16x32_bf16(qf[ks], kf, sf[j], 0, 0, 0);
            }

        // no-max softmax: e = 2^(s*cs); masked -> 0; l accumulated per-lane
        const bool diag = (kb == qt);
#pragma unroll
        for (int j = 0; j < 4; ++j)
#pragma unroll
            for (int ii = 0; ii < 4; ++ii) {
                float ev = EXP2F(sf[j][ii] * cs);
                if (diag && (j * 16 + lr > w * 16 + lg * 4 + ii)) ev = 0.f;
                lsum[ii] += ev;
                Pw[(lg * 4 + ii) * 76 + j * 16 + lr] = f2bf_fast(ev);  // C->LDS
            }

#pragma unroll
        for (int ks = 0; ks < 2; ++ks) {
            union { short8 v; shortx4 hh[2]; } pa;  // P A-frag: two 8B reads
            pa.hh[0] = *(const shortx4*)&Pw[lr * 76 + ks * 32 + lg * 8];
            pa.hh[1] = *(const shortx4*)&Pw[lr * 76 + ks * 32 + lg * 8 + 4];
#pragma unroll
            for (int j = 0; j < 4; ++j) {
                short8 vf = *(const short8*)&Vs[(j * 16 + lr) * 72 + ks * 32 + lg * 8];
                of[j] = __builtin_amdgcn_mfma_f32_16x16x32_bf16(pa.v, vf, of[j], 0, 0, 0);
            }
        }
        __syncthreads();
    }

    float rinv[4];
#pragma unroll
    for (int ii = 0; ii < 4; ++ii) {  // one l-reduction for the whole kernel
        float s = lsum[ii];
#pragma unroll
        for (int off = 1; off < 16; off <<= 1) s += __shfl_xor(s, off);
        rinv[ii] = 1.f / s;
    }
#pragma unroll
    for (int j = 0; j < 4; ++j)
#pragma unroll
        for (int ii = 0; ii < 4; ++ii)
            O[(size_t)(b * S_ + q0 + w * 16 + lg * 4 + ii) * D_ + h * DH_ + j * 16 + lr] =
                f2bf(of[j][ii] * rinv[ii]);
}

extern "C" void kernel_launch(void* const* d_in, const int* in_sizes, int n_in,
                              void* d_out, int out_size, void* d_ws, size_t ws_size,
                              hipStream_t stream) {
    (void)in_sizes; (void)n_in; (void)out_size; (void)ws_size;
    const float* x  = (const float*)d_in[0];
    const float* Wq = (const float*)d_in[1];
    const float* bq = (const float*)d_in[2];
    const float* Wk = (const float*)d_in[3];
    const float* bk = (const float*)d_in[4];
    const float* Wv = (const float*)d_in[5];
    const float* bv = (const float*)d_in[6];
    const float* Wo = (const float*)d_in[7];
    const float* bo = (const float*)d_in[8];

    // ws layout (u16 elems), 48 MB total:
    //   [0,3M) WqkvT  [3M,4M) WoT  [4M,16M) QKV  [16M,20M) Vt  [20M,24M) xbf -> reused as Am
    u16* ws    = (u16*)d_ws;
    u16* WqkvT = ws;
    u16* WoT   = ws + (size_t)3 * (1 << 20);
    u16* QKV   = ws + (size_t)4 * (1 << 20);
    u16* Vtm   = ws + (size_t)16 * (1 << 20);
    u16* xbf   = ws + (size_t)20 * (1 << 20);
    u16* Am    = ws + (size_t)20 * (1 << 20);

    convert_x<<<4096, 256, 0, stream>>>(x, xbf);
    transpose_w4<<<dim3(32, 32, 4), dim3(32, 8), 0, stream>>>(Wq, Wk, Wv, Wo, WqkvT, WoT);

    // QKV = xbf @ WqkvT^T + [bq|bk|bv]  (M=4096, N=3072)
    gemm_bt<128, 128, false><<<dim3(DQKV_ / 128, 4096 / 128), 256, 0, stream>>>(
        xbf, WqkvT, bq, bk, bv, QKV, 4096, DQKV_, 1024);

    transpose_headV<<<dim3(32, 32), 256, 0, stream>>>(QKV, Vtm);

    attn_mfma<<<dim3(32, 32), 256, 0, stream>>>(QKV, Vtm, Am);

    // out = Am @ WoT^T + bo  (M=4096, N=1024), fp32 out
    gemm_bt<64, 128, true><<<dim3(1024 / 128, 4096 / 64), 256, 0, stream>>>(
        Am, WoT, bo, bo, bo, d_out, 4096, 1024, 1024);
}

// Round 9
// 194.496 us; speedup vs baseline: 1.2708x; 1.0904x over previous
//
#include <hip/hip_runtime.h>

typedef unsigned short u16;
typedef __attribute__((ext_vector_type(8))) short short8;   // 8 bf16 (4 VGPRs) MFMA A/B frag
typedef __attribute__((ext_vector_type(4))) short shortx4;  // 4 bf16 (8B)
typedef __attribute__((ext_vector_type(4))) float floatx4;  // MFMA C/D frag

#define S_ 2048
#define D_ 1024
#define DQKV_ 3072
#define H_ 16
#define DH_ 64

#define EXP2F(x) __builtin_amdgcn_exp2f(x)

__device__ __forceinline__ float bf2f(u16 x) {
    union { unsigned int u; float f; } v; v.u = ((unsigned int)x) << 16; return v.f;
}
__device__ __forceinline__ u16 f2bf(float f) {  // RNE
    unsigned int u = __float_as_uint(f);
    return (u16)((u + 0x7fffu + ((u >> 16) & 1u)) >> 16);
}
__device__ __forceinline__ u16 f2bf_fast(float f) {  // round-to-nearest (ties up); operand >= 0
    return (u16)((__float_as_uint(f) + 0x8000u) >> 16);
}

// async global->LDS, 16B per lane; LDS dest is wave-uniform base + lane*16 (m97/m104)
__device__ __forceinline__ void async16(const void* g, void* l) {
    __builtin_amdgcn_global_load_lds(
        (const __attribute__((address_space(1))) unsigned int*)g,
        (__attribute__((address_space(3))) unsigned int*)l, 16, 0, 0);
}

// ---------------- xb = bf16(x), 4096x1024 ----------------
__global__ __launch_bounds__(256) void convert_x(const float* __restrict__ x, u16* __restrict__ xb) {
    const size_t i = ((size_t)blockIdx.x * 256 + threadIdx.x) * 4;
    float4 v = *(const float4*)&x[i];
    shortx4 h;
    h[0] = (short)f2bf(v.x); h[1] = (short)f2bf(v.y);
    h[2] = (short)f2bf(v.z); h[3] = (short)f2bf(v.w);
    *(shortx4*)&xb[i] = h;
}

// ------- fused W transposes: WqkvT[3072][1024] (=[Wq^T;Wk^T;Wv^T]) and WoT[1024][1024] -------
__global__ __launch_bounds__(256) void transpose_w4(const float* __restrict__ Wq, const float* __restrict__ Wk,
                                                    const float* __restrict__ Wv, const float* __restrict__ Wo,
                                                    u16* __restrict__ Wqkvt, u16* __restrict__ Wot) {
    __shared__ u16 tile[32][33];
    const int z = blockIdx.z;
    const float* W = (z == 0) ? Wq : (z == 1) ? Wk : (z == 2) ? Wv : Wo;
    u16* dst = (z == 3) ? Wot : (Wqkvt + (size_t)z * D_ * D_);
    const int tx = threadIdx.x, ty = threadIdx.y;
    const int n0 = blockIdx.x * 32, k0 = blockIdx.y * 32;
#pragma unroll
    for (int r = 0; r < 4; ++r) {
        int k = ty + r * 8;
        tile[k][tx] = f2bf(W[(size_t)(k0 + k) * D_ + n0 + tx]);
    }
    __syncthreads();
#pragma unroll
    for (int r = 0; r < 4; ++r) {
        int n = ty + r * 8;
        dst[(size_t)(n0 + n) * D_ + k0 + tx] = tile[tx][n];
    }
}

// ------- Vt[bh][d][s] = QKV[b*S+s][2048 + h*64 + d]  (per-head V transpose) -------
__global__ __launch_bounds__(256) void transpose_headV(const u16* __restrict__ QKV, u16* __restrict__ Vt) {
    __shared__ u16 tile[64 * 65];
    const int t = threadIdx.x;
    const int bh = blockIdx.y, b = bh >> 4, h = bh & 15;
    const int s0 = blockIdx.x << 6;
#pragma unroll
    for (int i = 0; i < 16; ++i) {
        int idx = t + (i << 8);
        int s = idx >> 6, d = idx & 63;
        tile[s * 65 + d] = QKV[(size_t)(b * S_ + s0 + s) * DQKV_ + 2048 + h * DH_ + d];
    }
    __syncthreads();
#pragma unroll
    for (int i = 0; i < 16; ++i) {
        int idx = t + (i << 8);
        int d = idx >> 6, s = idx & 63;
        Vt[((size_t)bh * DH_ + d) * S_ + s0 + s] = tile[s * 65 + d];
    }
}

// ------- C[M,N] = A[M,K] @ Bt[N,K]^T + bias; bf16 in, fp32 acc -------
// BMxBN tile, BK=32, packed LDS rows (64B) staged via global_load_lds width=16 (m97 pattern).
// 4 waves in 2x2 grid. Bias selected per-1024-col segment.
template <int BM, int BN, bool OUTF32>
__global__ __launch_bounds__(256) void gemm_bt(const u16* __restrict__ A, const u16* __restrict__ Bt,
                                               const float* __restrict__ b0, const float* __restrict__ b1,
                                               const float* __restrict__ b2, void* __restrict__ Cp,
                                               int M, int N, int Kd) {
    constexpr int FI = BM / 32, FJ = BN / 32;
    __shared__ __align__(16) u16 As[BM * 32];  // packed: required by global_load_lds lane-contiguity
    __shared__ __align__(16) u16 Bs[BN * 32];
    const int t = threadIdx.x;
    const int m0 = blockIdx.y * BM, n0 = blockIdx.x * BN;
    const int w = t >> 6, lane = t & 63;
    const int lr = lane & 15, lg = lane >> 4;
    const int wm = (w >> 1) * (BM / 2), wn = (w & 1) * (BN / 2);
    const int srow = lane >> 2, scol = (lane & 3) << 3;  // lane -> (row-in-16, k8)
    floatx4 acc[FI][FJ] = {};

    for (int k0 = 0; k0 < Kd; k0 += 32) {
#pragma unroll
        for (int c = 0; c < BM / 64; ++c) {  // one wave-inst stages 16 rows x 64B = 1KB
            int rbase = (w * (BM / 64) + c) * 16;
            async16(&A[(size_t)(m0 + rbase + srow) * Kd + k0 + scol], &As[rbase * 32]);
        }
#pragma unroll
        for (int c = 0; c < BN / 64; ++c) {
            int rbase = (w * (BN / 64) + c) * 16;
            async16(&Bt[(size_t)(n0 + rbase + srow) * Kd + k0 + scol], &Bs[rbase * 32]);
        }
        __syncthreads();  // drains vmcnt (global_load_lds) before use
        short8 af[FI], bfr[FJ];
#pragma unroll
        for (int i = 0; i < FI; ++i) af[i]  = *(const short8*)&As[(wm + i * 16 + lr) * 32 + lg * 8];
#pragma unroll
        for (int j = 0; j < FJ; ++j) bfr[j] = *(const short8*)&Bs[(wn + j * 16 + lr) * 32 + lg * 8];
#pragma unroll
        for (int i = 0; i < FI; ++i)
#pragma unroll
            for (int j = 0; j < FJ; ++j)
                acc[i][j] = __builtin_amdgcn_mfma_f32_16x16x32_bf16(af[i], bfr[j], acc[i][j], 0, 0, 0);
        __syncthreads();
    }

#pragma unroll
    for (int j = 0; j < FJ; ++j) {
        int col = n0 + wn + j * 16 + lr;
        const float* bp = (col < 1024) ? b0 : (col < 2048) ? b1 : b2;
        float bv = bp[col & 1023];
#pragma unroll
        for (int i = 0; i < FI; ++i) {
            int rb = m0 + wm + i * 16 + lg * 4;
#pragma unroll
            for (int ii = 0; ii < 4; ++ii) {
                float val = acc[i][j][ii] + bv;
                if (OUTF32) ((float*)Cp)[(size_t)(rb + ii) * N + col] = val;
                else        ((u16*)Cp)[(size_t)(rb + ii) * N + col] = f2bf(val);
            }
        }
    }
}

// ---------------- MFMA flash attention, async-DMA double-buffered ----------------
// grid (bh=32, qidx=32); qt = 31-qidx (LPT). 4 waves x 16 q-rows.
// K/V tiles staged via global_load_lds into XOR-swizzled packed LDS (row 128B,
// chunk c of row r stored at position c^(r&7) -> conflict-free b128 frag reads).
// Double-buffered, ONE barrier per k-tile: barrier drains DMA for tile k, then
// DMA for k+1 is issued into the other buffer and overlaps tile-k compute.
// No-max softmax (bounded scores -> exp2 exact). No held registers -> no spill.
__global__ __launch_bounds__(256) void attn_mfma(const u16* __restrict__ QKV, const u16* __restrict__ Vt,
                                                 u16* __restrict__ O) {
    __shared__ __align__(16) u16 KsA[2][64 * 64];  // [key][d], packed 128B rows, XOR-swizzled chunks
    __shared__ __align__(16) u16 VsA[2][64 * 64];  // [d][key]
    __shared__ __align__(16) u16 Ps[4 * 16 * 76];  // per-wave P [q][key], stride 76
    const int t = threadIdx.x, w = t >> 6, lane = t & 63;
    const int lr = lane & 15, lg = lane >> 4;
    const int bh = blockIdx.x, b = bh >> 4, h = bh & 15;
    const int qt = 31 - blockIdx.y;
    const int q0 = qt << 6;
    const float cs = 0.18033688f;  // (1/sqrt(64)) * log2(e)

    const u16* Kb  = QKV + (size_t)b * S_ * DQKV_ + 1024 + h * DH_;  // row stride DQKV_
    const u16* Vtb = Vt + (size_t)bh * DH_ * S_;                     // row stride S_
    u16* Pw = Ps + w * (16 * 76);

    const int rb = lane >> 3;               // row within 8-row staging group
    const int cc = ((lane & 7) ^ rb) << 3;  // swizzled source chunk (u16 offset)
    const int swz = lr & 7;                 // frag-read swizzle key (= row&7)

    short8 qf[2];  // Q A-frags: A[m=lr][k=ks*32+lg*8+j]
#pragma unroll
    for (int ks = 0; ks < 2; ++ks)
        qf[ks] = *(const short8*)&QKV[(size_t)(b * S_ + q0 + w * 16 + lr) * DQKV_ + h * DH_ + ks * 32 + lg * 8];

    floatx4 of[4] = {};  // O [16q][64d] C-layout: row=lg*4+ii, col=j*16+lr
    float lsum[4] = {0.f, 0.f, 0.f, 0.f};

    {   // prologue: DMA tile 0 into buffer 0 (wave w stages rows w*8.. and 32+w*8..)
        u16* Kd = &KsA[0][w * 512];
        u16* Vd = &VsA[0][w * 512];
        async16(&Kb[(size_t)(w * 8 + rb) * DQKV_ + cc], Kd);
        async16(&Kb[(size_t)(32 + w * 8 + rb) * DQKV_ + cc], Kd + 2048);
        async16(&Vtb[(size_t)(w * 8 + rb) * S_ + cc], Vd);
        async16(&Vtb[(size_t)(32 + w * 8 + rb) * S_ + cc], Vd + 2048);
    }

    for (int kb = 0; kb <= qt; ++kb) {
        const int cur = kb & 1;
        __syncthreads();  // implicit vmcnt(0) drain: buffer `cur` is ready; iterations separated
        if (kb < qt) {    // DMA next tile into the other buffer; overlaps compute below
            const int K1 = (kb + 1) << 6;
            u16* Kd = &KsA[cur ^ 1][w * 512];
            u16* Vd = &VsA[cur ^ 1][w * 512];
            async16(&Kb[(size_t)(K1 + w * 8 + rb) * DQKV_ + cc], Kd);
            async16(&Kb[(size_t)(K1 + 32 + w * 8 + rb) * DQKV_ + cc], Kd + 2048);
            async16(&Vtb[(size_t)(w * 8 + rb) * S_ + K1 + cc], Vd);
            async16(&Vtb[(size_t)(32 + w * 8 + rb) * S_ + K1 + cc], Vd + 2048);
        }
        const u16* Kc = KsA[cur];
        const u16* Vc = VsA[cur];

        floatx4 sf[4] = {};  // S [16q][64keys]
#pragma unroll
        for (int ks = 0; ks < 2; ++ks)
#pragma unroll
            for (int j = 0; j < 4; ++j) {
                short8 kf = *(const short8*)&Kc[(j * 16 + lr) * 64 + ((((ks << 2) + lg) ^ swz) << 3)];
                sf[j] = __builtin_amdgcn_mfma_f32_16x16x32_bf16(qf[ks], kf, sf[j], 0, 0, 0);
            }

        // no-max softmax: e = 2^(s*cs); masked -> 0; l accumulated per-lane
        const bool diag = (kb == qt);
#pragma unroll
        for (int j = 0; j < 4; ++j)
#pragma unroll
            for (int ii = 0; ii < 4; ++ii) {
                float ev = EXP2F(sf[j][ii] * cs);
                if (diag && (j * 16 + lr > w * 16 + lg * 4 + ii)) ev = 0.f;
                lsum[ii] += ev;
                Pw[(lg * 4 + ii) * 76 + j * 16 + lr] = f2bf_fast(ev);  // C->LDS
            }

#pragma unroll
        for (int ks = 0; ks < 2; ++ks) {
            union { short8 v; shortx4 hh[2]; } pa;  // P A-frag: two 8B reads
            pa.hh[0] = *(const shortx4*)&Pw[lr * 76 + ks * 32 + lg * 8];
            pa.hh[1] = *(const shortx4*)&Pw[lr * 76 + ks * 32 + lg * 8 + 4];
#pragma unroll
            for (int j = 0; j < 4; ++j) {
                short8 vf = *(const short8*)&Vc[(j * 16 + lr) * 64 + ((((ks << 2) + lg) ^ swz) << 3)];
                of[j] = __builtin_amdgcn_mfma_f32_16x16x32_bf16(pa.v, vf, of[j], 0, 0, 0);
            }
        }
    }

    float rinv[4];
#pragma unroll
    for (int ii = 0; ii < 4; ++ii) {  // one l-reduction for the whole kernel
        float s = lsum[ii];
#pragma unroll
        for (int off = 1; off < 16; off <<= 1) s += __shfl_xor(s, off);
        rinv[ii] = 1.f / s;
    }
#pragma unroll
    for (int j = 0; j < 4; ++j)
#pragma unroll
        for (int ii = 0; ii < 4; ++ii)
            O[(size_t)(b * S_ + q0 + w * 16 + lg * 4 + ii) * D_ + h * DH_ + j * 16 + lr] =
                f2bf(of[j][ii] * rinv[ii]);
}

extern "C" void kernel_launch(void* const* d_in, const int* in_sizes, int n_in,
                              void* d_out, int out_size, void* d_ws, size_t ws_size,
                              hipStream_t stream) {
    (void)in_sizes; (void)n_in; (void)out_size; (void)ws_size;
    const float* x  = (const float*)d_in[0];
    const float* Wq = (const float*)d_in[1];
    const float* bq = (const float*)d_in[2];
    const float* Wk = (const float*)d_in[3];
    const float* bk = (const float*)d_in[4];
    const float* Wv = (const float*)d_in[5];
    const float* bv = (const float*)d_in[6];
    const float* Wo = (const float*)d_in[7];
    const float* bo = (const float*)d_in[8];

    // ws layout (u16 elems), 48 MB total:
    //   [0,3M) WqkvT  [3M,4M) WoT  [4M,16M) QKV  [16M,20M) Vt  [20M,24M) xbf -> reused as Am
    u16* ws    = (u16*)d_ws;
    u16* WqkvT = ws;
    u16* WoT   = ws + (size_t)3 * (1 << 20);
    u16* QKV   = ws + (size_t)4 * (1 << 20);
    u16* Vtm   = ws + (size_t)16 * (1 << 20);
    u16* xbf   = ws + (size_t)20 * (1 << 20);
    u16* Am    = ws + (size_t)20 * (1 << 20);

    convert_x<<<4096, 256, 0, stream>>>(x, xbf);
    transpose_w4<<<dim3(32, 32, 4), dim3(32, 8), 0, stream>>>(Wq, Wk, Wv, Wo, WqkvT, WoT);

    // QKV = xbf @ WqkvT^T + [bq|bk|bv]  (M=4096, N=3072)
    gemm_bt<128, 128, false><<<dim3(DQKV_ / 128, 4096 / 128), 256, 0, stream>>>(
        xbf, WqkvT, bq, bk, bv, QKV, 4096, DQKV_, 1024);

    transpose_headV<<<dim3(32, 32), 256, 0, stream>>>(QKV, Vtm);

    attn_mfma<<<dim3(32, 32), 256, 0, stream>>>(QKV, Vtm, Am);

    // out = Am @ WoT^T + bo  (M=4096, N=1024), fp32 out
    gemm_bt<64, 128, true><<<dim3(1024 / 128, 4096 / 64), 256, 0, stream>>>(
        Am, WoT, bo, bo, bo, d_out, 4096, 1024, 1024);
}

// Round 10
// 190.975 us; speedup vs baseline: 1.2942x; 1.0184x over previous
//
#include <hip/hip_runtime.h>

typedef unsigned short u16;
typedef __attribute__((ext_vector_type(8))) short short8;   // 8 bf16 (4 VGPRs) MFMA A/B frag
typedef __attribute__((ext_vector_type(4))) short shortx4;  // 4 bf16 (8B)
typedef __attribute__((ext_vector_type(4))) float floatx4;  // MFMA C/D frag

#define S_ 2048
#define D_ 1024
#define DQKV_ 3072
#define H_ 16
#define DH_ 64

#define EXP2F(x) __builtin_amdgcn_exp2f(x)

__device__ __forceinline__ float bf2f(u16 x) {
    union { unsigned int u; float f; } v; v.u = ((unsigned int)x) << 16; return v.f;
}
__device__ __forceinline__ u16 f2bf(float f) {  // RNE
    unsigned int u = __float_as_uint(f);
    return (u16)((u + 0x7fffu + ((u >> 16) & 1u)) >> 16);
}
__device__ __forceinline__ u16 f2bf_fast(float f) {  // round-to-nearest (ties up); operand >= 0
    return (u16)((__float_as_uint(f) + 0x8000u) >> 16);
}

// async global->LDS, 16B per lane; LDS dest is wave-uniform base + lane*16 (m97/m104)
__device__ __forceinline__ void async16(const void* g, void* l) {
    __builtin_amdgcn_global_load_lds(
        (const __attribute__((address_space(1))) unsigned int*)g,
        (__attribute__((address_space(3))) unsigned int*)l, 16, 0, 0);
}

// ---------------- xb = bf16(x), 4096x1024 ----------------
__global__ __launch_bounds__(256) void convert_x(const float* __restrict__ x, u16* __restrict__ xb) {
    const size_t i = ((size_t)blockIdx.x * 256 + threadIdx.x) * 4;
    float4 v = *(const float4*)&x[i];
    shortx4 h;
    h[0] = (short)f2bf(v.x); h[1] = (short)f2bf(v.y);
    h[2] = (short)f2bf(v.z); h[3] = (short)f2bf(v.w);
    *(shortx4*)&xb[i] = h;
}

// ------- fused W transposes: WqkvT[3072][1024] (=[Wq^T;Wk^T;Wv^T]) and WoT[1024][1024] -------
__global__ __launch_bounds__(256) void transpose_w4(const float* __restrict__ Wq, const float* __restrict__ Wk,
                                                    const float* __restrict__ Wv, const float* __restrict__ Wo,
                                                    u16* __restrict__ Wqkvt, u16* __restrict__ Wot) {
    __shared__ u16 tile[32][33];
    const int z = blockIdx.z;
    const float* W = (z == 0) ? Wq : (z == 1) ? Wk : (z == 2) ? Wv : Wo;
    u16* dst = (z == 3) ? Wot : (Wqkvt + (size_t)z * D_ * D_);
    const int tx = threadIdx.x, ty = threadIdx.y;
    const int n0 = blockIdx.x * 32, k0 = blockIdx.y * 32;
#pragma unroll
    for (int r = 0; r < 4; ++r) {
        int k = ty + r * 8;
        tile[k][tx] = f2bf(W[(size_t)(k0 + k) * D_ + n0 + tx]);
    }
    __syncthreads();
#pragma unroll
    for (int r = 0; r < 4; ++r) {
        int n = ty + r * 8;
        dst[(size_t)(n0 + n) * D_ + k0 + tx] = tile[tx][n];
    }
}

// ------- Vt[bh][d][s] = QKV[b*S+s][2048 + h*64 + d]  (per-head V transpose) -------
__global__ __launch_bounds__(256) void transpose_headV(const u16* __restrict__ QKV, u16* __restrict__ Vt) {
    __shared__ u16 tile[64 * 65];
    const int t = threadIdx.x;
    const int bh = blockIdx.y, b = bh >> 4, h = bh & 15;
    const int s0 = blockIdx.x << 6;
#pragma unroll
    for (int i = 0; i < 16; ++i) {
        int idx = t + (i << 8);
        int s = idx >> 6, d = idx & 63;
        tile[s * 65 + d] = QKV[(size_t)(b * S_ + s0 + s) * DQKV_ + 2048 + h * DH_ + d];
    }
    __syncthreads();
#pragma unroll
    for (int i = 0; i < 16; ++i) {
        int idx = t + (i << 8);
        int d = idx >> 6, s = idx & 63;
        Vt[((size_t)bh * DH_ + d) * S_ + s0 + s] = tile[s * 65 + d];
    }
}

// ------- C[M,N] = A[M,K] @ Bt[N,K]^T + bias; bf16 in, fp32 acc -------
// BMxBN tile, BK=32. Async-DMA DOUBLE-buffered, ONE barrier per K-iter (R9
// attention pattern): barrier's implicit vmcnt(0) drains the DMA issued one
// full iteration earlier; prefetch for k+1 overlaps MFMA on k.
// 4 waves in 2x2 grid. Bias selected per-1024-col segment.
template <int BM, int BN, bool OUTF32>
__global__ __launch_bounds__(256) void gemm_bt(const u16* __restrict__ A, const u16* __restrict__ Bt,
                                               const float* __restrict__ b0, const float* __restrict__ b1,
                                               const float* __restrict__ b2, void* __restrict__ Cp,
                                               int M, int N, int Kd) {
    constexpr int FI = BM / 32, FJ = BN / 32;
    __shared__ __align__(16) u16 As[2][BM * 32];  // packed: global_load_lds lane-contiguity
    __shared__ __align__(16) u16 Bs[2][BN * 32];
    const int t = threadIdx.x;
    const int m0 = blockIdx.y * BM, n0 = blockIdx.x * BN;
    const int w = t >> 6, lane = t & 63;
    const int lr = lane & 15, lg = lane >> 4;
    const int wm = (w >> 1) * (BM / 2), wn = (w & 1) * (BN / 2);
    const int srow = lane >> 2, scol = (lane & 3) << 3;  // lane -> (row-in-16, k8)
    floatx4 acc[FI][FJ] = {};

    auto stage = [&](int buf, int k0) {
#pragma unroll
        for (int c = 0; c < BM / 64; ++c) {  // one wave-inst stages 16 rows x 64B = 1KB
            int rbase = (w * (BM / 64) + c) * 16;
            async16(&A[(size_t)(m0 + rbase + srow) * Kd + k0 + scol], &As[buf][rbase * 32]);
        }
#pragma unroll
        for (int c = 0; c < BN / 64; ++c) {
            int rbase = (w * (BN / 64) + c) * 16;
            async16(&Bt[(size_t)(n0 + rbase + srow) * Kd + k0 + scol], &Bs[buf][rbase * 32]);
        }
    };

    stage(0, 0);  // prologue
    const int nk = Kd / 32;
    for (int kk = 0; kk < nk; ++kk) {
        const int cur = kk & 1;
        __syncthreads();  // drains vmcnt(0): buffer `cur` ready; all waves done with cur^1
        if (kk + 1 < nk) stage(cur ^ 1, (kk + 1) * 32);

        short8 af[FI], bfr[FJ];
#pragma unroll
        for (int i = 0; i < FI; ++i) af[i]  = *(const short8*)&As[cur][(wm + i * 16 + lr) * 32 + lg * 8];
#pragma unroll
        for (int j = 0; j < FJ; ++j) bfr[j] = *(const short8*)&Bs[cur][(wn + j * 16 + lr) * 32 + lg * 8];
#pragma unroll
        for (int i = 0; i < FI; ++i)
#pragma unroll
            for (int j = 0; j < FJ; ++j)
                acc[i][j] = __builtin_amdgcn_mfma_f32_16x16x32_bf16(af[i], bfr[j], acc[i][j], 0, 0, 0);
    }

#pragma unroll
    for (int j = 0; j < FJ; ++j) {
        int col = n0 + wn + j * 16 + lr;
        const float* bp = (col < 1024) ? b0 : (col < 2048) ? b1 : b2;
        float bv = bp[col & 1023];
#pragma unroll
        for (int i = 0; i < FI; ++i) {
            int rb = m0 + wm + i * 16 + lg * 4;
#pragma unroll
            for (int ii = 0; ii < 4; ++ii) {
                float val = acc[i][j][ii] + bv;
                if (OUTF32) ((float*)Cp)[(size_t)(rb + ii) * N + col] = val;
                else        ((u16*)Cp)[(size_t)(rb + ii) * N + col] = f2bf(val);
            }
        }
    }
}

// ---------------- MFMA flash attention, async-DMA double-buffered ----------------
// grid (bh=32, qidx=32); qt = 31-qidx (LPT). 4 waves x 16 q-rows.
// K/V via global_load_lds into XOR-swizzled packed LDS; double-buffered, one
// barrier per k-tile. P buffer ALSO XOR-swizzled (stride 64): b16 scatter stays
// <=2-way (free), A-frag read becomes one b128. LDS total = 40960 B exactly ->
// 4 blocks/CU (was 3 at stride-76). No-max softmax (bounded scores, exact).
__global__ __launch_bounds__(256) void attn_mfma(const u16* __restrict__ QKV, const u16* __restrict__ Vt,
                                                 u16* __restrict__ O) {
    __shared__ __align__(16) u16 KsA[2][64 * 64];  // [key][d], packed 128B rows, XOR-swizzled chunks
    __shared__ __align__(16) u16 VsA[2][64 * 64];  // [d][key]
    __shared__ __align__(16) u16 Ps[4 * 16 * 64];  // per-wave P [q][key], XOR-swizzled chunks
    const int t = threadIdx.x, w = t >> 6, lane = t & 63;
    const int lr = lane & 15, lg = lane >> 4;
    const int bh = blockIdx.x, b = bh >> 4, h = bh & 15;
    const int qt = 31 - blockIdx.y;
    const int q0 = qt << 6;
    const float cs = 0.18033688f;  // (1/sqrt(64)) * log2(e)

    const u16* Kb  = QKV + (size_t)b * S_ * DQKV_ + 1024 + h * DH_;  // row stride DQKV_
    const u16* Vtb = Vt + (size_t)bh * DH_ * S_;                     // row stride S_
    u16* Pw = Ps + w * (16 * 64);

    const int rb = lane >> 3;               // row within 8-row staging group
    const int cc = ((lane & 7) ^ rb) << 3;  // swizzled source chunk (u16 offset)
    const int swz = lr & 7;                 // frag-read swizzle key (= row&7)

    short8 qf[2];  // Q A-frags: A[m=lr][k=ks*32+lg*8+j]
#pragma unroll
    for (int ks = 0; ks < 2; ++ks)
        qf[ks] = *(const short8*)&QKV[(size_t)(b * S_ + q0 + w * 16 + lr) * DQKV_ + h * DH_ + ks * 32 + lg * 8];

    floatx4 of[4] = {};  // O [16q][64d] C-layout: row=lg*4+ii, col=j*16+lr
    float lsum[4] = {0.f, 0.f, 0.f, 0.f};

    {   // prologue: DMA tile 0 into buffer 0 (wave w stages rows w*8.. and 32+w*8..)
        u16* Kd = &KsA[0][w * 512];
        u16* Vd = &VsA[0][w * 512];
        async16(&Kb[(size_t)(w * 8 + rb) * DQKV_ + cc], Kd);
        async16(&Kb[(size_t)(32 + w * 8 + rb) * DQKV_ + cc], Kd + 2048);
        async16(&Vtb[(size_t)(w * 8 + rb) * S_ + cc], Vd);
        async16(&Vtb[(size_t)(32 + w * 8 + rb) * S_ + cc], Vd + 2048);
    }

    for (int kb = 0; kb <= qt; ++kb) {
        const int cur = kb & 1;
        __syncthreads();  // implicit vmcnt(0) drain: buffer `cur` is ready
        if (kb < qt) {    // DMA next tile into the other buffer; overlaps compute below
            const int K1 = (kb + 1) << 6;
            u16* Kd = &KsA[cur ^ 1][w * 512];
            u16* Vd = &VsA[cur ^ 1][w * 512];
            async16(&Kb[(size_t)(K1 + w * 8 + rb) * DQKV_ + cc], Kd);
            async16(&Kb[(size_t)(K1 + 32 + w * 8 + rb) * DQKV_ + cc], Kd + 2048);
            async16(&Vtb[(size_t)(w * 8 + rb) * S_ + K1 + cc], Vd);
            async16(&Vtb[(size_t)(32 + w * 8 + rb) * S_ + K1 + cc], Vd + 2048);
        }
        const u16* Kc = KsA[cur];
        const u16* Vc = VsA[cur];

        floatx4 sf[4] = {};  // S [16q][64keys]
#pragma unroll
        for (int ks = 0; ks < 2; ++ks)
#pragma unroll
            for (int j = 0; j < 4; ++j) {
                short8 kf = *(const short8*)&Kc[(j * 16 + lr) * 64 + ((((ks << 2) + lg) ^ swz) << 3)];
                sf[j] = __builtin_amdgcn_mfma_f32_16x16x32_bf16(qf[ks], kf, sf[j], 0, 0, 0);
            }

        // no-max softmax: e = 2^(s*cs); masked -> 0; l accumulated per-lane.
        // P write: row r=lg*4+ii, col c=j*16+lr stored at chunk (c>>3)^(r&7).
        const bool diag = (kb == qt);
#pragma unroll
        for (int j = 0; j < 4; ++j)
#pragma unroll
            for (int ii = 0; ii < 4; ++ii) {
                float ev = EXP2F(sf[j][ii] * cs);
                if (diag && (j * 16 + lr > w * 16 + lg * 4 + ii)) ev = 0.f;
                lsum[ii] += ev;
                int r = lg * 4 + ii;
                int chunk = ((j * 2 + (lr >> 3)) ^ (r & 7));
                Pw[r * 64 + (chunk << 3) + (lr & 7)] = f2bf_fast(ev);
            }

#pragma unroll
        for (int ks = 0; ks < 2; ++ks) {
            // P A-frag: row lr, k-chunk ks*4+lg, same XOR -> one 16B-aligned b128
            short8 pa = *(const short8*)&Pw[lr * 64 + ((((ks << 2) + lg) ^ swz) << 3)];
#pragma unroll
            for (int j = 0; j < 4; ++j) {
                short8 vf = *(const short8*)&Vc[(j * 16 + lr) * 64 + ((((ks << 2) + lg) ^ swz) << 3)];
                of[j] = __builtin_amdgcn_mfma_f32_16x16x32_bf16(pa, vf, of[j], 0, 0, 0);
            }
        }
    }

    float rinv[4];
#pragma unroll
    for (int ii = 0; ii < 4; ++ii) {  // one l-reduction for the whole kernel
        float s = lsum[ii];
#pragma unroll
        for (int off = 1; off < 16; off <<= 1) s += __shfl_xor(s, off);
        rinv[ii] = 1.f / s;
    }
#pragma unroll
    for (int j = 0; j < 4; ++j)
#pragma unroll
        for (int ii = 0; ii < 4; ++ii)
            O[(size_t)(b * S_ + q0 + w * 16 + lg * 4 + ii) * D_ + h * DH_ + j * 16 + lr] =
                f2bf(of[j][ii] * rinv[ii]);
}

extern "C" void kernel_launch(void* const* d_in, const int* in_sizes, int n_in,
                              void* d_out, int out_size, void* d_ws, size_t ws_size,
                              hipStream_t stream) {
    (void)in_sizes; (void)n_in; (void)out_size; (void)ws_size;
    const float* x  = (const float*)d_in[0];
    const float* Wq = (const float*)d_in[1];
    const float* bq = (const float*)d_in[2];
    const float* Wk = (const float*)d_in[3];
    const float* bk = (const float*)d_in[4];
    const float* Wv = (const float*)d_in[5];
    const float* bv = (const float*)d_in[6];
    const float* Wo = (const float*)d_in[7];
    const float* bo = (const float*)d_in[8];

    // ws layout (u16 elems), 48 MB total:
    //   [0,3M) WqkvT  [3M,4M) WoT  [4M,16M) QKV  [16M,20M) Vt  [20M,24M) xbf -> reused as Am
    u16* ws    = (u16*)d_ws;
    u16* WqkvT = ws;
    u16* WoT   = ws + (size_t)3 * (1 << 20);
    u16* QKV   = ws + (size_t)4 * (1 << 20);
    u16* Vtm   = ws + (size_t)16 * (1 << 20);
    u16* xbf   = ws + (size_t)20 * (1 << 20);
    u16* Am    = ws + (size_t)20 * (1 << 20);

    convert_x<<<4096, 256, 0, stream>>>(x, xbf);
    transpose_w4<<<dim3(32, 32, 4), dim3(32, 8), 0, stream>>>(Wq, Wk, Wv, Wo, WqkvT, WoT);

    // QKV = xbf @ WqkvT^T + [bq|bk|bv]  (M=4096, N=3072)
    gemm_bt<128, 128, false><<<dim3(DQKV_ / 128, 4096 / 128), 256, 0, stream>>>(
        xbf, WqkvT, bq, bk, bv, QKV, 4096, DQKV_, 1024);

    transpose_headV<<<dim3(32, 32), 256, 0, stream>>>(QKV, Vtm);

    attn_mfma<<<dim3(32, 32), 256, 0, stream>>>(QKV, Vtm, Am);

    // out = Am @ WoT^T + bo  (M=4096, N=1024), fp32 out
    gemm_bt<64, 128, true><<<dim3(1024 / 128, 4096 / 64), 256, 0, stream>>>(
        Am, WoT, bo, bo, bo, d_out, 4096, 1024, 1024);
}